// Round 1
// 866.926 us; speedup vs baseline: 1.0697x; 1.0697x over previous
//
#include <hip/hip_runtime.h>
#include <cstdint>
#include <cstddef>

// Problem constants
#define Bsz   16384
#define INsz  10
#define Hsz   1024
#define N4    4096      // 4 gates * H
#define NK    34        // K-steps of 32: K2 = 1088 = 1024 hid + 10 x + 1.0 + pad
#define SIXH  6144
#define GDI   7
#define LR    0.001f
#define NPART 512       // partial-grad blocks in gd pass

typedef _Float16 f16;
typedef __attribute__((ext_vector_type(8))) _Float16 f16x8;
typedef __attribute__((ext_vector_type(4))) _Float16 f16x4;
typedef __attribute__((ext_vector_type(4))) float    f32x4;

// async global->LDS, 16B per lane; LDS dest = wave-uniform base + lane*16.
__device__ __forceinline__ void llds16(const f16* g, f16* l) {
    __builtin_amdgcn_global_load_lds(
        (__attribute__((address_space(1))) void*)(uintptr_t)g,
        (__attribute__((address_space(3))) void*)(uintptr_t)l,
        16, 0, 0);
}

__device__ __forceinline__ float sigm(float z)   { return 1.f / (1.f + __expf(-z)); }
__device__ __forceinline__ float tanh_f(float z) { return 1.f - 2.f / (__expf(2.f * z) + 1.f); }

// ---------------------------------------------------------------------------
// Fragment-panelized operand layout (shared by prepA/prepU/gemm):
// matrix is split into 128-row tiles x NK K-steps of 32. Each (tile,ks) tile
// (128x32 f16 = 8 KB) is stored as 8 slabs x 64 lanes x 8 f16, where slab rb
// holds rows rb*16 + r and lane l = q*16+r holds elems k = q*8..q*8+7 —
// exactly the 16x16x32 MFMA fragment order. Staging = linear 16B copies;
// fragment ds_read = lane-consecutive 16 B (zero bank conflicts).
// chunk index c = ((tile*NK + ks)*8 + rb)*64 + l ; element base = c*8.
// ---------------------------------------------------------------------------

// A2 [16384 x 1088]: cols 0..1023 = hidden, 1024..1033 = x, 1034 = 1.0, rest 0.
__global__ void k_prepA(const float* __restrict__ hid, const float* __restrict__ x,
                        f16* __restrict__ A2) {
    int c = blockIdx.x * 256 + threadIdx.x;       // 16384*1088/8 = 2,228,224 chunks
    int mt  = c / 17408;                          // 17408 = NK*512 chunks per 128-row tile
    int rem = c - mt * 17408;
    int ks  = rem >> 9;
    int rb  = (rem >> 6) & 7;
    int l   = rem & 63;
    int row = mt * 128 + rb * 16 + (l & 15);
    int k0  = ks * 32 + (l >> 4) * 8;
    f16x8 v;
    if (k0 + 8 <= Hsz) {                          // uniform per (ks,q): ks<32 always here
        float4 t0 = *(const float4*)&hid[(size_t)row * Hsz + k0];
        float4 t1 = *(const float4*)&hid[(size_t)row * Hsz + k0 + 4];
        v[0]=(f16)t0.x; v[1]=(f16)t0.y; v[2]=(f16)t0.z; v[3]=(f16)t0.w;
        v[4]=(f16)t1.x; v[5]=(f16)t1.y; v[6]=(f16)t1.z; v[7]=(f16)t1.w;
    } else {                                      // K-extension: x | 1.0 | zeros
#pragma unroll
        for (int e = 0; e < 8; ++e) {
            int k = k0 + e;
            float f = 0.f;
            if (k < Hsz + INsz)       f = x[(size_t)row * INsz + (k - Hsz)];
            else if (k == Hsz + INsz) f = 1.0f;
            v[e] = (f16)f;
        }
    }
    *(f16x8*)&A2[(size_t)c * 8] = v;
}

// U2 [4096 x 1088] panelized; n-tile nt covers output cols {g*1024 + nt*32 + h'}
// at within-tile row cc = g*32 + h'. cols 0..1023 = U_g[h], 1024..1033 = W_g[h],
// 1034 = bias_g[h], rest 0.
__global__ void k_prepU(const float* __restrict__ Uf, const float* __restrict__ Ui,
                        const float* __restrict__ Uc, const float* __restrict__ Uo,
                        const float* __restrict__ Wf, const float* __restrict__ Wi,
                        const float* __restrict__ Wc, const float* __restrict__ Wo,
                        const float* __restrict__ bf_, const float* __restrict__ bi_,
                        const float* __restrict__ bc_, const float* __restrict__ bo_,
                        f16* __restrict__ U2) {
    int c = blockIdx.x * 256 + threadIdx.x;       // 4096*1088/8 = 557,056 chunks
    int nt  = c / 17408;
    int rem = c - nt * 17408;
    int ks  = rem >> 9;
    int rb  = (rem >> 6) & 7;
    int l   = rem & 63;
    int cc  = rb * 16 + (l & 15);                 // within-tile col (output col slot)
    int g   = cc >> 5;                            // wave-uniform (rb uniform per 64 chunks)
    int h   = nt * 32 + (cc & 31);
    int k0  = ks * 32 + (l >> 4) * 8;
    const float* U = (g == 0) ? Uf : (g == 1) ? Ui : (g == 2) ? Uc : Uo;
    f16x8 v;
    if (k0 + 8 <= Hsz) {
        float4 t0 = *(const float4*)&U[(size_t)h * Hsz + k0];
        float4 t1 = *(const float4*)&U[(size_t)h * Hsz + k0 + 4];
        v[0]=(f16)t0.x; v[1]=(f16)t0.y; v[2]=(f16)t0.z; v[3]=(f16)t0.w;
        v[4]=(f16)t1.x; v[5]=(f16)t1.y; v[6]=(f16)t1.z; v[7]=(f16)t1.w;
    } else {
        const float* W  = (g == 0) ? Wf  : (g == 1) ? Wi  : (g == 2) ? Wc  : Wo;
        const float* Bb = (g == 0) ? bf_ : (g == 1) ? bi_ : (g == 2) ? bc_ : bo_;
#pragma unroll
        for (int e = 0; e < 8; ++e) {
            int k = k0 + e;
            float f = 0.f;
            if (k < Hsz + INsz)       f = W[h * INsz + (k - Hsz)];
            else if (k == Hsz + INsz) f = Bb[h];
            v[e] = (f16)f;
        }
    }
    *(f16x8*)&U2[(size_t)c * 8] = v;
}

__global__ void k_zero(float* __restrict__ p, int n) {
    int i = blockIdx.x * 256 + threadIdx.x;
    if (i < n) p[i] = 0.f;
}

// ---------------------------------------------------------------------------
// GEMM + fused activation epilogue.
// 128x128 tile, BK=32, 256 threads (2x2 waves of 64x64), 16x16x32 MFMA.
// Ring-3 LDS double(triple)-buffer with counted vmcnt(8) — loads stay in
// flight across barriers (T3/T4). Fragment reads are conflict-free (panelized).
// Epilogue: acc -> LDS image (XOR-swizzled) -> per-(row,h-octet) activation:
// writes activated f,i,ct,o (f16) to rt4 in the ORIGINAL g*1024+h layout,
// and c_new (fp32) to c_out. Replaces the old k_epi pass entirely.
// IMG: XOR row into 8-col groups so image writes/reads spread banks.
#define IMG(r, cidx) ((r) * 128 + ((cidx) ^ (((r) & 15) << 3)))

__global__ __launch_bounds__(256, 3) void k_gemm(const f16* __restrict__ A2,
                                                 const f16* __restrict__ U2,
                                                 const float* __restrict__ c_in,
                                                 f16* __restrict__ rt4,
                                                 float* __restrict__ c_out) {
    __shared__ __align__(16) f16 sm[3 * 8192];   // 48 KB: slot s = A(4096) | B(4096)
    const int bid = blockIdx.x;
    const int swz = ((bid & 7) << 9) | (bid >> 3);   // XCD swizzle (4096 % 8 == 0)
    const int bm = swz >> 5, bn = swz & 31;
    const int tid = threadIdx.x, wave = tid >> 6, lane = tid & 63;
    const int wr = wave >> 1, wc = wave & 1;
    const int r = lane & 15, q = lane >> 4;

    const f16* gA = A2 + (size_t)bm * (NK * 4096);
    const f16* gB = U2 + (size_t)bn * (NK * 4096);

    auto stage = [&](int ks) {
        f16* s = &sm[(ks % 3) * 8192];
        const f16* a = gA + (size_t)ks * 4096;
        const f16* b = gB + (size_t)ks * 4096;
        llds16(a + tid * 8,        &s[tid * 8]);
        llds16(a + 2048 + tid * 8, &s[2048 + tid * 8]);
        llds16(b + tid * 8,        &s[4096 + tid * 8]);
        llds16(b + 2048 + tid * 8, &s[6144 + tid * 8]);
    };

    f32x4 acc[4][4];
#pragma unroll
    for (int i = 0; i < 4; ++i)
#pragma unroll
        for (int j = 0; j < 4; ++j) acc[i][j] = (f32x4){0.f, 0.f, 0.f, 0.f};

    stage(0); stage(1);                           // 8 llds16 in flight

    for (int ks = 0; ks < NK; ++ks) {
        // counted vmcnt: after wait, stages ks+1,ks+2 (8 calls) remain in flight;
        // oldest (stage ks) has landed. Never drain to 0 in the main loop.
        if (ks + 2 < NK) {
            stage(ks + 2);
            asm volatile("s_waitcnt vmcnt(8)" ::: "memory");
        } else if (ks + 1 < NK) {
            asm volatile("s_waitcnt vmcnt(4)" ::: "memory");
        } else {
            asm volatile("s_waitcnt vmcnt(0)" ::: "memory");
        }
        __builtin_amdgcn_s_barrier();             // all waves' stage(ks) visible
        __builtin_amdgcn_sched_barrier(0);        // pin reads below the barrier
        const f16* s = &sm[(ks % 3) * 8192];
        f16x8 af[4], bf[4];
#pragma unroll
        for (int i = 0; i < 4; ++i)
            af[i] = *(const f16x8*)&s[(wr * 4 + i) * 512 + lane * 8];
#pragma unroll
        for (int j = 0; j < 4; ++j)
            bf[j] = *(const f16x8*)&s[4096 + (wc * 4 + j) * 512 + lane * 8];
        asm volatile("s_waitcnt lgkmcnt(0)" ::: "memory");
        __builtin_amdgcn_sched_barrier(0);        // rule 18: MFMA must not hoist
        __builtin_amdgcn_s_barrier();             // slot ks%3 now reusable next+1
#pragma unroll
        for (int i = 0; i < 4; ++i)
#pragma unroll
            for (int j = 0; j < 4; ++j)
                acc[i][j] = __builtin_amdgcn_mfma_f32_16x16x32_f16(af[i], bf[j], acc[i][j], 0, 0, 0);
    }

    // ---- fused epilogue ----
    // 1) acc -> LDS image [128][128] f16 (swizzled). C/D: col=lane&15, row=(lane>>4)*4+reg.
    f16* img = sm;
#pragma unroll
    for (int i = 0; i < 4; ++i)
#pragma unroll
        for (int j = 0; j < 4; ++j)
#pragma unroll
            for (int reg = 0; reg < 4; ++reg) {
                int row_l = wr * 64 + i * 16 + q * 4 + reg;
                int col_l = wc * 64 + j * 16 + r;
                img[IMG(row_l, col_l)] = (f16)acc[i][j][reg];
            }
    asm volatile("s_waitcnt lgkmcnt(0)" ::: "memory");
    __builtin_amdgcn_s_barrier();
    __builtin_amdgcn_sched_barrier(0);

    // 2) per (row, h-octet): activate all 4 gates, compute c_new; vector stores.
    const int bcol = bn * 32;                     // global h base for this tile
#pragma unroll
    for (int s_ = 0; s_ < 2; ++s_) {
        int a  = s_ * 256 + tid;                  // 512 assignments: 128 rows x 4 octets
        int row = a >> 2, ho = (a & 3) * 8;
        int grow = bm * 128 + row;
        f16x8 pf = *(const f16x8*)&img[IMG(row,      ho)];
        f16x8 pi = *(const f16x8*)&img[IMG(row, 32 + ho)];
        f16x8 pc = *(const f16x8*)&img[IMG(row, 64 + ho)];
        f16x8 po = *(const f16x8*)&img[IMG(row, 96 + ho)];
        float4 c0 = *(const float4*)&c_in[(size_t)grow * Hsz + bcol + ho];
        float4 c1 = *(const float4*)&c_in[(size_t)grow * Hsz + bcol + ho + 4];
        float cv[8] = {c0.x, c0.y, c0.z, c0.w, c1.x, c1.y, c1.z, c1.w};
        f16x8 of, oi, oc, oo;
        float cn[8];
#pragma unroll
        for (int e = 0; e < 8; ++e) {
            float f  = sigm((float)pf[e]);
            float i_ = sigm((float)pi[e]);
            float ct = tanh_f((float)pc[e]);
            float o  = sigm((float)po[e]);
            cn[e] = f * cv[e] + i_ * ct;
            of[e] = (f16)f; oi[e] = (f16)i_; oc[e] = (f16)ct; oo[e] = (f16)o;
        }
        size_t rb_ = (size_t)grow * N4 + bcol + ho;
        *(f16x8*)&rt4[rb_]        = of;
        *(f16x8*)&rt4[rb_ + 1024] = oi;
        *(f16x8*)&rt4[rb_ + 2048] = oc;
        *(f16x8*)&rt4[rb_ + 3072] = oo;
        *(float4*)&c_out[(size_t)grow * Hsz + bcol + ho]     = (float4){cn[0], cn[1], cn[2], cn[3]};
        *(float4*)&c_out[(size_t)grow * Hsz + bcol + ho + 4] = (float4){cn[4], cn[5], cn[6], cn[7]};
    }
}

// ---------------------------------------------------------------------------
// Fused GD iteration: one pass over rt4 + c_new. Block = 256 threads, 32 rows.
// Features: [0,4096) = rt4 (f,i,ct,o); [4096,5120) = c_new (fp32); [5120,6144) = h_std
// (recomputed = o * tanh(cn)). Thread t owns cols {t*8}, {2048+t*8}, cn {t*4}, hs {t*4}.
__global__ __launch_bounds__(256) void k_gd(const f16* __restrict__ rt4,
                                            const float* __restrict__ cn,
                                            const float* __restrict__ mp,
                                            const float* __restrict__ theta,
                                            float* __restrict__ part) {
    const int tid = threadIdx.x;
    const int r0 = blockIdx.x * 32;
    const int wave = tid >> 6, lane = tid & 63;

    float thA[8], thB[8], thC[4], thD[4];
    float grA[8] = {0}, grB[8] = {0}, grC[4] = {0}, grD[4] = {0};
#pragma unroll
    for (int k = 0; k < 8; ++k) {
        thA[k] = theta[tid * 8 + k];
        thB[k] = theta[2048 + tid * 8 + k];
    }
#pragma unroll
    for (int k = 0; k < 4; ++k) {
        thC[k] = theta[4096 + tid * 4 + k];
        thD[k] = theta[5120 + tid * 4 + k];
    }

    __shared__ float red[16];   // [rr][wave]

    for (int rb = 0; rb < 32; rb += 4) {
        f16x8 dA[4], dB[4];
        f32x4 dC[4];
        float hs[4][4];
        float s[4];
#pragma unroll
        for (int rr = 0; rr < 4; ++rr) {
            const size_t row = (size_t)(r0 + rb + rr);
            dA[rr] = *(const f16x8*)&rt4[row * N4 + tid * 8];
            dB[rr] = *(const f16x8*)&rt4[row * N4 + 2048 + tid * 8];
            dC[rr] = *(const f32x4*)&cn[row * Hsz + tid * 4];
            f16x4 dO = *(const f16x4*)&rt4[row * N4 + 3072 + tid * 4];
            float a = 0.f;
#pragma unroll
            for (int k = 0; k < 8; ++k) a += (float)dA[rr][k] * thA[k];
#pragma unroll
            for (int k = 0; k < 8; ++k) a += (float)dB[rr][k] * thB[k];
#pragma unroll
            for (int k = 0; k < 4; ++k) {
                float h = (float)dO[k] * tanh_f(dC[rr][k]);
                hs[rr][k] = h;
                a += dC[rr][k] * thC[k] + h * thD[k];
            }
            s[rr] = a;
        }
#pragma unroll
        for (int rr = 0; rr < 4; ++rr)
#pragma unroll
            for (int off = 32; off > 0; off >>= 1)
                s[rr] += __shfl_xor(s[rr], off, 64);
        if (lane == 0) {
#pragma unroll
            for (int rr = 0; rr < 4; ++rr) red[rr * 4 + wave] = s[rr];
        }
        __syncthreads();
        float e[4];
#pragma unroll
        for (int rr = 0; rr < 4; ++rr)
            e[rr] = (red[rr * 4 + 0] + red[rr * 4 + 1] + red[rr * 4 + 2] + red[rr * 4 + 3])
                    - mp[r0 + rb + rr];
        __syncthreads();
#pragma unroll
        for (int rr = 0; rr < 4; ++rr) {
#pragma unroll
            for (int k = 0; k < 8; ++k) {
                grA[k] += e[rr] * (float)dA[rr][k];
                grB[k] += e[rr] * (float)dB[rr][k];
            }
#pragma unroll
            for (int k = 0; k < 4; ++k) {
                grC[k] += e[rr] * dC[rr][k];
                grD[k] += e[rr] * hs[rr][k];
            }
        }
    }

    float* pb = &part[(size_t)blockIdx.x * SIXH];
#pragma unroll
    for (int k = 0; k < 8; ++k) {
        pb[tid * 8 + k]        = grA[k];
        pb[2048 + tid * 8 + k] = grB[k];
    }
#pragma unroll
    for (int k = 0; k < 4; ++k) {
        pb[4096 + tid * 4 + k] = grC[k];
        pb[5120 + tid * 4 + k] = grD[k];
    }
}

// Reduce NPART partial grads -> theta update (deterministic fixed-order sums).
__global__ void k_reduce(const float* __restrict__ part, float* __restrict__ theta) {
    __shared__ float sred[256];
    const int tid = threadIdx.x;
    const int c = (tid & 31) + blockIdx.x * 32;
    const int pl = tid >> 5;
    float s = 0.f;
    for (int p = pl; p < NPART; p += 8) s += part[(size_t)p * SIXH + c];
    sred[tid] = s;
    __syncthreads();
    if (pl == 0) {
        float acc = s;
#pragma unroll
        for (int k = 1; k < 8; ++k) acc += sred[k * 32 + (tid & 31)];
        theta[c] -= (2.f * LR / (float)Bsz) * acc;
    }
}

// ---------------------------------------------------------------------------
// argmax over per-gate mean|theta|; result (0..5) stored as float in out_c[0]
// (fixed-order reduction -> deterministic across runs).
__global__ void k_argmax(const float* __restrict__ theta, float* __restrict__ outc) {
    __shared__ float w[6][4];
    const int tid = threadIdx.x;   // 256
    const int wave = tid >> 6, lane = tid & 63;
    for (int g = 0; g < 6; ++g) {
        float s = 0.f;
        for (int j = tid; j < 1024; j += 256) s += fabsf(theta[g * 1024 + j]);
#pragma unroll
        for (int off = 32; off > 0; off >>= 1) s += __shfl_xor(s, off, 64);
        if (lane == 0) w[g][wave] = s;
    }
    __syncthreads();
    if (tid == 0) {
        int best = 0;
        float bv = w[0][0] + w[0][1] + w[0][2] + w[0][3];
        for (int g = 1; g < 6; ++g) {
            float v = w[g][0] + w[g][1] + w[g][2] + w[g][3];
            if (v > bv) { bv = v; best = g; }   // strict >: first max wins (matches argmax)
        }
        outc[0] = (float)best;
    }
}

// Gather h_new. Reads rt4 (ws) + out_c only; writes out_h only -> no race with
// the scratch that lived in out_h (all dead by now).
__global__ void k_gather(const f16* __restrict__ rt4, const float* __restrict__ cnp,
                         float* __restrict__ outh) {
    const int idx = (int)cnp[0];
    int t = blockIdx.x * 256 + threadIdx.x;   // Bsz*Hsz/4 threads
    int b = t >> 8, h4 = (t & 255) * 4;
    float* o = &outh[(size_t)b * Hsz + h4];
    if (idx < 4) {
        f16x4 v = *(const f16x4*)&rt4[(size_t)b * N4 + idx * 1024 + h4];
#pragma unroll
        for (int k = 0; k < 4; ++k) o[k] = (float)v[k];
    } else if (idx == 4) {
        f32x4 v = *(const f32x4*)&cnp[(size_t)b * Hsz + h4];
#pragma unroll
        for (int k = 0; k < 4; ++k) o[k] = v[k];
    } else {
        f16x4 ov = *(const f16x4*)&rt4[(size_t)b * N4 + 3072 + h4];
        f32x4 cv = *(const f32x4*)&cnp[(size_t)b * Hsz + h4];
#pragma unroll
        for (int k = 0; k < 4; ++k) o[k] = (float)ov[k] * tanh_f(cv[k]);
    }
}

// Restore c_new[0] (clobbered by the smuggled argmax index) and fix out_h[0]
// for the idx==4/5 paths that read the clobbered value.
__global__ void k_fix(const f16* __restrict__ rt4, const float* __restrict__ c_in,
                      float* __restrict__ out) {
    if (threadIdx.x == 0 && blockIdx.x == 0) {
        int idx = (int)out[(size_t)Bsz * Hsz];
        float f  = (float)rt4[0];
        float i_ = (float)rt4[1024];
        float ct = (float)rt4[2048];
        float o  = (float)rt4[3072];
        float cn = f * c_in[0] + i_ * ct;
        out[(size_t)Bsz * Hsz] = cn;
        if (idx == 4)      out[0] = cn;
        else if (idx == 5) out[0] = o * tanh_f(cn);
    }
}

// ---------------------------------------------------------------------------
extern "C" void kernel_launch(void* const* d_in, const int* in_sizes, int n_in,
                              void* d_out, int out_size, void* d_ws, size_t ws_size,
                              hipStream_t stream) {
    const float* x    = (const float*)d_in[0];
    const float* hid  = (const float*)d_in[1];
    const float* c    = (const float*)d_in[2];
    const float* mp   = (const float*)d_in[3];
    const float* Wf_w = (const float*)d_in[4];
    const float* Wf_b = (const float*)d_in[5];
    const float* Uf_w = (const float*)d_in[6];
    const float* Wi_w = (const float*)d_in[7];
    const float* Wi_b = (const float*)d_in[8];
    const float* Ui_w = (const float*)d_in[9];
    const float* Wc_w = (const float*)d_in[10];
    const float* Wc_b = (const float*)d_in[11];
    const float* Uc_w = (const float*)d_in[12];
    const float* Wo_w = (const float*)d_in[13];
    const float* Wo_b = (const float*)d_in[14];
    const float* Uo_w = (const float*)d_in[15];
    float* out  = (float*)d_out;                       // [h_new | c_new] fp32
    float* outc = out + (size_t)Bsz * Hsz;

    // ws: rt4 only — exactly 134,217,728 B (128 MiB)
    f16* rt4 = (f16*)d_ws;
    // scratch inside out's h_new half (67.1 MB; all dead before k_gather writes):
    uint8_t* oh = (uint8_t*)d_out;
    f16*   U2    = (f16*)oh;                           // 4096*1088*2  =  8,912,896 B
    f16*   A2    = (f16*)(oh + 8912896);               // 16384*1088*2 = 35,651,584 B
    float* theta = (float*)(oh + 44564480);            // 24,576 B
    float* part  = (float*)(oh + 44589056);            // 512*6144*4 = 12,582,912 B (ends 57.2 MB < 67.1 MB)

    k_prepU<<<2176, 256, 0, stream>>>(Uf_w, Ui_w, Uc_w, Uo_w,
                                      Wf_w, Wi_w, Wc_w, Wo_w,
                                      Wf_b, Wi_b, Wc_b, Wo_b, U2);
    k_prepA<<<8704, 256, 0, stream>>>(hid, x, A2);
    k_gemm<<<4096, 256, 0, stream>>>(A2, U2, c, rt4, outc);   // + fused activation epi
    k_zero<<<24, 256, 0, stream>>>(theta, SIXH);
    for (int it = 0; it < GDI; ++it) {
        k_gd<<<NPART, 256, 0, stream>>>(rt4, outc, mp, theta, part);
        k_reduce<<<SIXH / 32, 256, 0, stream>>>(part, theta);
    }
    k_argmax<<<1, 256, 0, stream>>>(theta, outc);
    k_gather<<<(Bsz * Hsz / 4) / 256, 256, 0, stream>>>(rt4, outc, out);
    k_fix<<<1, 64, 0, stream>>>(rt4, c, out);
}

// Round 2
// 778.776 us; speedup vs baseline: 1.1908x; 1.1132x over previous
//
#include <hip/hip_runtime.h>
#include <cstdint>
#include <cstddef>

// Problem constants
#define Bsz   16384
#define INsz  10
#define Hsz   1024
#define N4    4096      // 4 gates * H
#define NK    34        // K-steps of 32: K2 = 1088 = 1024 hid + 10 x + 1.0 + pad
#define SIXH  6144
#define GDI   7
#define LR    0.001f
#define NPART 1024      // partial-grad blocks in gd pass (4 blocks/CU)
#define RPB   (Bsz / NPART)   // 16 rows per gd block

typedef _Float16 f16;
typedef __attribute__((ext_vector_type(8))) _Float16 f16x8;
typedef __attribute__((ext_vector_type(4))) _Float16 f16x4;
typedef __attribute__((ext_vector_type(4))) float    f32x4;

// async global->LDS, 16B per lane; LDS dest = wave-uniform base + lane*16.
__device__ __forceinline__ void llds16(const f16* g, f16* l) {
    __builtin_amdgcn_global_load_lds(
        (__attribute__((address_space(1))) void*)(uintptr_t)g,
        (__attribute__((address_space(3))) void*)(uintptr_t)l,
        16, 0, 0);
}

__device__ __forceinline__ float sigm(float z)   { return 1.f / (1.f + __expf(-z)); }
__device__ __forceinline__ float tanh_f(float z) { return 1.f - 2.f / (__expf(2.f * z) + 1.f); }

// ---------------------------------------------------------------------------
// Fragment-panelized operand layout (shared by prepA/prepU/gemm):
// matrix is split into 128-row tiles x NK K-steps of 32. Each (tile,ks) tile
// (128x32 f16 = 8 KB) is stored as 8 slabs x 64 lanes x 8 f16, where slab rb
// holds rows rb*16 + r and lane l = q*16+r holds elems k = q*8..q*8+7 —
// exactly the 16x16x32 MFMA fragment order. Staging = linear 16B copies;
// fragment ds_read = lane-consecutive 16 B (zero bank conflicts).
// chunk index c = ((tile*NK + ks)*8 + rb)*64 + l ; element base = c*8.
// ---------------------------------------------------------------------------

// A2 [16384 x 1088]: cols 0..1023 = hidden, 1024..1033 = x, 1034 = 1.0, rest 0.
__global__ void k_prepA(const float* __restrict__ hid, const float* __restrict__ x,
                        f16* __restrict__ A2) {
    int c = blockIdx.x * 256 + threadIdx.x;       // 16384*1088/8 = 2,228,224 chunks
    int mt  = c / 17408;                          // 17408 = NK*512 chunks per 128-row tile
    int rem = c - mt * 17408;
    int ks  = rem >> 9;
    int rb  = (rem >> 6) & 7;
    int l   = rem & 63;
    int row = mt * 128 + rb * 16 + (l & 15);
    int k0  = ks * 32 + (l >> 4) * 8;
    f16x8 v;
    if (k0 + 8 <= Hsz) {                          // uniform per (ks,q): ks<32 always here
        float4 t0 = *(const float4*)&hid[(size_t)row * Hsz + k0];
        float4 t1 = *(const float4*)&hid[(size_t)row * Hsz + k0 + 4];
        v[0]=(f16)t0.x; v[1]=(f16)t0.y; v[2]=(f16)t0.z; v[3]=(f16)t0.w;
        v[4]=(f16)t1.x; v[5]=(f16)t1.y; v[6]=(f16)t1.z; v[7]=(f16)t1.w;
    } else {                                      // K-extension: x | 1.0 | zeros
#pragma unroll
        for (int e = 0; e < 8; ++e) {
            int k = k0 + e;
            float f = 0.f;
            if (k < Hsz + INsz)       f = x[(size_t)row * INsz + (k - Hsz)];
            else if (k == Hsz + INsz) f = 1.0f;
            v[e] = (f16)f;
        }
    }
    *(f16x8*)&A2[(size_t)c * 8] = v;
}

// U2 [4096 x 1088] panelized; n-tile nt covers output cols {g*1024 + nt*32 + h'}
// at within-tile row cc = g*32 + h'. cols 0..1023 = U_g[h], 1024..1033 = W_g[h],
// 1034 = bias_g[h], rest 0.
__global__ void k_prepU(const float* __restrict__ Uf, const float* __restrict__ Ui,
                        const float* __restrict__ Uc, const float* __restrict__ Uo,
                        const float* __restrict__ Wf, const float* __restrict__ Wi,
                        const float* __restrict__ Wc, const float* __restrict__ Wo,
                        const float* __restrict__ bf_, const float* __restrict__ bi_,
                        const float* __restrict__ bc_, const float* __restrict__ bo_,
                        f16* __restrict__ U2) {
    int c = blockIdx.x * 256 + threadIdx.x;       // 4096*1088/8 = 557,056 chunks
    int nt  = c / 17408;
    int rem = c - nt * 17408;
    int ks  = rem >> 9;
    int rb  = (rem >> 6) & 7;
    int l   = rem & 63;
    int cc  = rb * 16 + (l & 15);                 // within-tile col (output col slot)
    int g   = cc >> 5;                            // wave-uniform (rb uniform per 64 chunks)
    int h   = nt * 32 + (cc & 31);
    int k0  = ks * 32 + (l >> 4) * 8;
    const float* U = (g == 0) ? Uf : (g == 1) ? Ui : (g == 2) ? Uc : Uo;
    f16x8 v;
    if (k0 + 8 <= Hsz) {
        float4 t0 = *(const float4*)&U[(size_t)h * Hsz + k0];
        float4 t1 = *(const float4*)&U[(size_t)h * Hsz + k0 + 4];
        v[0]=(f16)t0.x; v[1]=(f16)t0.y; v[2]=(f16)t0.z; v[3]=(f16)t0.w;
        v[4]=(f16)t1.x; v[5]=(f16)t1.y; v[6]=(f16)t1.z; v[7]=(f16)t1.w;
    } else {
        const float* W  = (g == 0) ? Wf  : (g == 1) ? Wi  : (g == 2) ? Wc  : Wo;
        const float* Bb = (g == 0) ? bf_ : (g == 1) ? bi_ : (g == 2) ? bc_ : bo_;
#pragma unroll
        for (int e = 0; e < 8; ++e) {
            int k = k0 + e;
            float f = 0.f;
            if (k < Hsz + INsz)       f = W[h * INsz + (k - Hsz)];
            else if (k == Hsz + INsz) f = Bb[h];
            v[e] = (f16)f;
        }
    }
    *(f16x8*)&U2[(size_t)c * 8] = v;
}

__global__ void k_zero(float* __restrict__ p, int n) {
    int i = blockIdx.x * 256 + threadIdx.x;
    if (i < n) p[i] = 0.f;
}

// ---------------------------------------------------------------------------
// GEMM + fused activation epilogue.
// 128x128 tile, BK=32, 256 threads (2x2 waves of 64x64), 16x16x32 MFMA.
// Ring-3 LDS double(triple)-buffer with counted vmcnt(8) — loads stay in
// flight across barriers (T3/T4). Fragment reads are conflict-free (panelized).
// Epilogue: acc -> LDS image (XOR-swizzled) -> per-(row,h-octet) activation:
// writes activated f,i,ct,o (f16) to rt4 in the ORIGINAL g*1024+h layout,
// and c_new (fp32) to c_out.
// IMG: XOR row into 8-col groups so image writes/reads spread banks.
#define IMG(r, cidx) ((r) * 128 + ((cidx) ^ (((r) & 15) << 3)))

__global__ __launch_bounds__(256, 3) void k_gemm(const f16* __restrict__ A2,
                                                 const f16* __restrict__ U2,
                                                 const float* __restrict__ c_in,
                                                 f16* __restrict__ rt4,
                                                 float* __restrict__ c_out) {
    __shared__ __align__(16) f16 sm[3 * 8192];   // 48 KB: slot s = A(4096) | B(4096)
    const int bid = blockIdx.x;
    const int swz = ((bid & 7) << 9) | (bid >> 3);   // XCD swizzle (4096 % 8 == 0)
    const int bm = swz >> 5, bn = swz & 31;
    const int tid = threadIdx.x, wave = tid >> 6, lane = tid & 63;
    const int wr = wave >> 1, wc = wave & 1;
    const int r = lane & 15, q = lane >> 4;

    const f16* gA = A2 + (size_t)bm * (NK * 4096);
    const f16* gB = U2 + (size_t)bn * (NK * 4096);

    auto stage = [&](int ks) {
        f16* s = &sm[(ks % 3) * 8192];
        const f16* a = gA + (size_t)ks * 4096;
        const f16* b = gB + (size_t)ks * 4096;
        llds16(a + tid * 8,        &s[tid * 8]);
        llds16(a + 2048 + tid * 8, &s[2048 + tid * 8]);
        llds16(b + tid * 8,        &s[4096 + tid * 8]);
        llds16(b + 2048 + tid * 8, &s[6144 + tid * 8]);
    };

    f32x4 acc[4][4];
#pragma unroll
    for (int i = 0; i < 4; ++i)
#pragma unroll
        for (int j = 0; j < 4; ++j) acc[i][j] = (f32x4){0.f, 0.f, 0.f, 0.f};

    stage(0); stage(1);                           // 8 llds16 in flight

    for (int ks = 0; ks < NK; ++ks) {
        // counted vmcnt: after wait, stages ks+1,ks+2 (8 calls) remain in flight;
        // oldest (stage ks) has landed. Never drain to 0 in the main loop.
        if (ks + 2 < NK) {
            stage(ks + 2);
            asm volatile("s_waitcnt vmcnt(8)" ::: "memory");
        } else if (ks + 1 < NK) {
            asm volatile("s_waitcnt vmcnt(4)" ::: "memory");
        } else {
            asm volatile("s_waitcnt vmcnt(0)" ::: "memory");
        }
        __builtin_amdgcn_s_barrier();             // all waves' stage(ks) visible
        __builtin_amdgcn_sched_barrier(0);        // pin reads below the barrier
        const f16* s = &sm[(ks % 3) * 8192];
        f16x8 af[4], bf[4];
#pragma unroll
        for (int i = 0; i < 4; ++i)
            af[i] = *(const f16x8*)&s[(wr * 4 + i) * 512 + lane * 8];
#pragma unroll
        for (int j = 0; j < 4; ++j)
            bf[j] = *(const f16x8*)&s[4096 + (wc * 4 + j) * 512 + lane * 8];
        asm volatile("s_waitcnt lgkmcnt(0)" ::: "memory");
        __builtin_amdgcn_sched_barrier(0);        // rule 18: MFMA must not hoist
        __builtin_amdgcn_s_barrier();             // slot ks%3 now reusable next+1
#pragma unroll
        for (int i = 0; i < 4; ++i)
#pragma unroll
            for (int j = 0; j < 4; ++j)
                acc[i][j] = __builtin_amdgcn_mfma_f32_16x16x32_f16(af[i], bf[j], acc[i][j], 0, 0, 0);
    }

    // ---- fused epilogue ----
    // 1) acc -> LDS image [128][128] f16 (swizzled). C/D: col=lane&15, row=(lane>>4)*4+reg.
    f16* img = sm;
#pragma unroll
    for (int i = 0; i < 4; ++i)
#pragma unroll
        for (int j = 0; j < 4; ++j)
#pragma unroll
            for (int reg = 0; reg < 4; ++reg) {
                int row_l = wr * 64 + i * 16 + q * 4 + reg;
                int col_l = wc * 64 + j * 16 + r;
                img[IMG(row_l, col_l)] = (f16)acc[i][j][reg];
            }
    asm volatile("s_waitcnt lgkmcnt(0)" ::: "memory");
    __builtin_amdgcn_s_barrier();
    __builtin_amdgcn_sched_barrier(0);

    // 2) per (row, h-octet): activate all 4 gates, compute c_new; vector stores.
    const int bcol = bn * 32;                     // global h base for this tile
#pragma unroll
    for (int s_ = 0; s_ < 2; ++s_) {
        int a  = s_ * 256 + tid;                  // 512 assignments: 128 rows x 4 octets
        int row = a >> 2, ho = (a & 3) * 8;
        int grow = bm * 128 + row;
        f16x8 pf = *(const f16x8*)&img[IMG(row,      ho)];
        f16x8 pi = *(const f16x8*)&img[IMG(row, 32 + ho)];
        f16x8 pc = *(const f16x8*)&img[IMG(row, 64 + ho)];
        f16x8 po = *(const f16x8*)&img[IMG(row, 96 + ho)];
        float4 c0 = *(const float4*)&c_in[(size_t)grow * Hsz + bcol + ho];
        float4 c1 = *(const float4*)&c_in[(size_t)grow * Hsz + bcol + ho + 4];
        float cv[8] = {c0.x, c0.y, c0.z, c0.w, c1.x, c1.y, c1.z, c1.w};
        f16x8 of, oi, oc, oo;
        float cn[8];
#pragma unroll
        for (int e = 0; e < 8; ++e) {
            float f  = sigm((float)pf[e]);
            float i_ = sigm((float)pi[e]);
            float ct = tanh_f((float)pc[e]);
            float o  = sigm((float)po[e]);
            cn[e] = f * cv[e] + i_ * ct;
            of[e] = (f16)f; oi[e] = (f16)i_; oc[e] = (f16)ct; oo[e] = (f16)o;
        }
        size_t rb_ = (size_t)grow * N4 + bcol + ho;
        *(f16x8*)&rt4[rb_]        = of;
        *(f16x8*)&rt4[rb_ + 1024] = oi;
        *(f16x8*)&rt4[rb_ + 2048] = oc;
        *(f16x8*)&rt4[rb_ + 3072] = oo;
        *(float4*)&c_out[(size_t)grow * Hsz + bcol + ho]     = (float4){cn[0], cn[1], cn[2], cn[3]};
        *(float4*)&c_out[(size_t)grow * Hsz + bcol + ho + 4] = (float4){cn[4], cn[5], cn[6], cn[7]};
    }
}

// ---------------------------------------------------------------------------
// Fused GD iteration: one pass over rt4 + c_new. Block = 256 threads, RPB=16 rows.
// Thread t owns 4-col slices at t*4 within EACH feature block:
//   f, i, ct, o (f16 from rt4), cn (fp32), hs = o*tanh(cn) recomputed locally.
// No duplicate o read (48 B/row/thread). Row-group = 2 keeps VGPR < 128 so
// __launch_bounds__(256,4) holds 4 waves/EU; grid = 1024 -> 4 blocks/CU.
__global__ __launch_bounds__(256, 4) void k_gd(const f16* __restrict__ rt4,
                                               const float* __restrict__ cn,
                                               const float* __restrict__ mp,
                                               const float* __restrict__ theta,
                                               float* __restrict__ part) {
    const int tid = threadIdx.x;
    const int r0 = blockIdx.x * RPB;
    const int wave = tid >> 6, lane = tid & 63;
    const int c4 = tid * 4;

    f32x4 thG[4], thC, thD;
    f32x4 grG[4], grC, grD;
#pragma unroll
    for (int g = 0; g < 4; ++g) {
        thG[g] = *(const f32x4*)&theta[g * 1024 + c4];
        grG[g] = (f32x4){0.f, 0.f, 0.f, 0.f};
    }
    thC = *(const f32x4*)&theta[4096 + c4];
    thD = *(const f32x4*)&theta[5120 + c4];
    grC = (f32x4){0.f, 0.f, 0.f, 0.f};
    grD = (f32x4){0.f, 0.f, 0.f, 0.f};

    __shared__ float red[8];   // [rr][wave]

    for (int rb = 0; rb < RPB; rb += 2) {
        f16x4 dG[2][4];
        f32x4 dC[2], hs[2];
        float s[2];
#pragma unroll
        for (int rr = 0; rr < 2; ++rr) {
            const size_t row = (size_t)(r0 + rb + rr);
#pragma unroll
            for (int g = 0; g < 4; ++g)
                dG[rr][g] = *(const f16x4*)&rt4[row * N4 + g * 1024 + c4];
            dC[rr] = *(const f32x4*)&cn[row * Hsz + c4];
            float a = 0.f;
#pragma unroll
            for (int g = 0; g < 4; ++g)
#pragma unroll
                for (int k = 0; k < 4; ++k) a += (float)dG[rr][g][k] * thG[g][k];
#pragma unroll
            for (int k = 0; k < 4; ++k) {
                float h = (float)dG[rr][3][k] * tanh_f(dC[rr][k]);
                hs[rr][k] = h;
                a += dC[rr][k] * thC[k] + h * thD[k];
            }
            s[rr] = a;
        }
#pragma unroll
        for (int rr = 0; rr < 2; ++rr)
#pragma unroll
            for (int off = 32; off > 0; off >>= 1)
                s[rr] += __shfl_xor(s[rr], off, 64);
        if (lane == 0) {
            red[wave]     = s[0];
            red[4 + wave] = s[1];
        }
        __syncthreads();
        float e[2];
#pragma unroll
        for (int rr = 0; rr < 2; ++rr)
            e[rr] = (red[rr * 4 + 0] + red[rr * 4 + 1] + red[rr * 4 + 2] + red[rr * 4 + 3])
                    - mp[r0 + rb + rr];
        __syncthreads();
#pragma unroll
        for (int rr = 0; rr < 2; ++rr) {
#pragma unroll
            for (int g = 0; g < 4; ++g)
#pragma unroll
                for (int k = 0; k < 4; ++k) grG[g][k] += e[rr] * (float)dG[rr][g][k];
#pragma unroll
            for (int k = 0; k < 4; ++k) {
                grC[k] += e[rr] * dC[rr][k];
                grD[k] += e[rr] * hs[rr][k];
            }
        }
    }

    float* pb = &part[(size_t)blockIdx.x * SIXH];
#pragma unroll
    for (int g = 0; g < 4; ++g) *(f32x4*)&pb[g * 1024 + c4] = grG[g];
    *(f32x4*)&pb[4096 + c4] = grC;
    *(f32x4*)&pb[5120 + c4] = grD;
}

// Reduce NPART partial grads -> theta update (deterministic fixed-order sums).
__global__ void k_reduce(const float* __restrict__ part, float* __restrict__ theta) {
    __shared__ float sred[256];
    const int tid = threadIdx.x;
    const int c = (tid & 31) + blockIdx.x * 32;
    const int pl = tid >> 5;
    float s = 0.f;
#pragma unroll 4
    for (int p = pl; p < NPART; p += 8) s += part[(size_t)p * SIXH + c];
    sred[tid] = s;
    __syncthreads();
    if (pl == 0) {
        float acc = s;
#pragma unroll
        for (int k = 1; k < 8; ++k) acc += sred[k * 32 + (tid & 31)];
        theta[c] -= (2.f * LR / (float)Bsz) * acc;
    }
}

// ---------------------------------------------------------------------------
// argmax over per-gate mean|theta|; result (0..5) stored as float in out_c[0]
// (fixed-order reduction -> deterministic across runs).
__global__ void k_argmax(const float* __restrict__ theta, float* __restrict__ outc) {
    __shared__ float w[6][4];
    const int tid = threadIdx.x;   // 256
    const int wave = tid >> 6, lane = tid & 63;
    for (int g = 0; g < 6; ++g) {
        float s = 0.f;
        for (int j = tid; j < 1024; j += 256) s += fabsf(theta[g * 1024 + j]);
#pragma unroll
        for (int off = 32; off > 0; off >>= 1) s += __shfl_xor(s, off, 64);
        if (lane == 0) w[g][wave] = s;
    }
    __syncthreads();
    if (tid == 0) {
        int best = 0;
        float bv = w[0][0] + w[0][1] + w[0][2] + w[0][3];
        for (int g = 1; g < 6; ++g) {
            float v = w[g][0] + w[g][1] + w[g][2] + w[g][3];
            if (v > bv) { bv = v; best = g; }   // strict >: first max wins (matches argmax)
        }
        outc[0] = (float)best;
    }
}

// Gather h_new. Reads rt4 (ws) + out_c only; writes out_h only -> no race with
// the scratch that lived in out_h (all dead by now).
__global__ void k_gather(const f16* __restrict__ rt4, const float* __restrict__ cnp,
                         float* __restrict__ outh) {
    const int idx = (int)cnp[0];
    int t = blockIdx.x * 256 + threadIdx.x;   // Bsz*Hsz/4 threads
    int b = t >> 8, h4 = (t & 255) * 4;
    float* o = &outh[(size_t)b * Hsz + h4];
    if (idx < 4) {
        f16x4 v = *(const f16x4*)&rt4[(size_t)b * N4 + idx * 1024 + h4];
#pragma unroll
        for (int k = 0; k < 4; ++k) o[k] = (float)v[k];
    } else if (idx == 4) {
        f32x4 v = *(const f32x4*)&cnp[(size_t)b * Hsz + h4];
#pragma unroll
        for (int k = 0; k < 4; ++k) o[k] = v[k];
    } else {
        f16x4 ov = *(const f16x4*)&rt4[(size_t)b * N4 + 3072 + h4];
        f32x4 cv = *(const f32x4*)&cnp[(size_t)b * Hsz + h4];
#pragma unroll
        for (int k = 0; k < 4; ++k) o[k] = (float)ov[k] * tanh_f(cv[k]);
    }
}

// Restore c_new[0] (clobbered by the smuggled argmax index) and fix out_h[0]
// for the idx==4/5 paths that read the clobbered value.
__global__ void k_fix(const f16* __restrict__ rt4, const float* __restrict__ c_in,
                      float* __restrict__ out) {
    if (threadIdx.x == 0 && blockIdx.x == 0) {
        int idx = (int)out[(size_t)Bsz * Hsz];
        float f  = (float)rt4[0];
        float i_ = (float)rt4[1024];
        float ct = (float)rt4[2048];
        float o  = (float)rt4[3072];
        float cn = f * c_in[0] + i_ * ct;
        out[(size_t)Bsz * Hsz] = cn;
        if (idx == 4)      out[0] = cn;
        else if (idx == 5) out[0] = o * tanh_f(cn);
    }
}

// ---------------------------------------------------------------------------
extern "C" void kernel_launch(void* const* d_in, const int* in_sizes, int n_in,
                              void* d_out, int out_size, void* d_ws, size_t ws_size,
                              hipStream_t stream) {
    const float* x    = (const float*)d_in[0];
    const float* hid  = (const float*)d_in[1];
    const float* c    = (const float*)d_in[2];
    const float* mp   = (const float*)d_in[3];
    const float* Wf_w = (const float*)d_in[4];
    const float* Wf_b = (const float*)d_in[5];
    const float* Uf_w = (const float*)d_in[6];
    const float* Wi_w = (const float*)d_in[7];
    const float* Wi_b = (const float*)d_in[8];
    const float* Ui_w = (const float*)d_in[9];
    const float* Wc_w = (const float*)d_in[10];
    const float* Wc_b = (const float*)d_in[11];
    const float* Uc_w = (const float*)d_in[12];
    const float* Wo_w = (const float*)d_in[13];
    const float* Wo_b = (const float*)d_in[14];
    const float* Uo_w = (const float*)d_in[15];
    float* out  = (float*)d_out;                       // [h_new | c_new] fp32
    float* outc = out + (size_t)Bsz * Hsz;

    // ws: rt4 only — exactly 134,217,728 B (128 MiB)
    f16* rt4 = (f16*)d_ws;
    // scratch inside out's h_new half (67.1 MB). Lifetimes are stream-ordered:
    //   U2 [0, 8.9M) + A2 [8.9M, 44.6M): written by preps, read by gemm, then dead.
    //   part [0, 25.17M) + theta [25.17M, +24KB): written AFTER gemm -> overlay OK.
    //   k_gather overwrites everything at the end (all dead by then).
    uint8_t* oh = (uint8_t*)d_out;
    f16*   U2    = (f16*)oh;                           // 4096*1088*2  =  8,912,896 B
    f16*   A2    = (f16*)(oh + 8912896);               // 16384*1088*2 = 35,651,584 B
    float* part  = (float*)oh;                         // 1024*6144*4  = 25,165,824 B
    float* theta = (float*)(oh + 25165824);            // 24,576 B (ends 25.19M < 67.1M)

    k_prepU<<<2176, 256, 0, stream>>>(Uf_w, Ui_w, Uc_w, Uo_w,
                                      Wf_w, Wi_w, Wc_w, Wo_w,
                                      Wf_b, Wi_b, Wc_b, Wo_b, U2);
    k_prepA<<<8704, 256, 0, stream>>>(hid, x, A2);
    k_gemm<<<4096, 256, 0, stream>>>(A2, U2, c, rt4, outc);   // + fused activation epi
    k_zero<<<24, 256, 0, stream>>>(theta, SIXH);
    for (int it = 0; it < GDI; ++it) {
        k_gd<<<NPART, 256, 0, stream>>>(rt4, outc, mp, theta, part);
        k_reduce<<<SIXH / 32, 256, 0, stream>>>(part, theta);
    }
    k_argmax<<<1, 256, 0, stream>>>(theta, outc);
    k_gather<<<(Bsz * Hsz / 4) / 256, 256, 0, stream>>>(rt4, outc, out);
    k_fix<<<1, 64, 0, stream>>>(rt4, c, out);
}